// Round 8
// baseline (51.124 us; speedup 1.0000x reference)
//
#include <hip/hip_runtime.h>
#include <hip/hip_cooperative_groups.h>
#include <cmath>

// Problem constants (fixed by the reference)
#define B_ 256
#define I_ 1024
#define O_ 1024

typedef __attribute__((ext_vector_type(8))) short short8;   // 8 bf16 = 4 VGPRs
typedef __attribute__((ext_vector_type(4))) float f32x4;

// float -> bf16 bits, round-to-nearest-even (inputs finite after clamp)
__device__ inline unsigned f2bf(float f) {
  union { float f; unsigned u; } c;
  c.f = f;
  unsigned u = c.u;
  return (u + 0x7FFFu + ((u >> 16) & 1u)) >> 16;
}

// fast log(tanh(100|x|)) = log((1-t)/(1+t)), t = e^{-200|x|}  (HW exp/log)
// x==0: log(0) = -inf -> clamped to -1e30; exp(sum)=0 downstream (delta=0). ✓
__device__ inline float fast_lt(float xv) {
  float z = 100.0f * fabsf(xv);
  float t = __expf(-2.0f * z);
  float lt = __logf((1.0f - t) / (1.0f + t));
  return fmaxf(lt, -1e30f);
}

// ---------------------------------------------------------------------------
// Single COOPERATIVE kernel. 256 blocks x 512 threads (8 waves) -> 1 block/CU.
// Phase A: exactly-once fp32->bf16 prep into ws (weights: 4096 elems/block,
//   8/thread; x: 1024 elems/block on threads 0..127).
// grid.sync()
// Phase B: round-4 GEMM body (best measured): 32x32 tile, intra-block
//   split-K (wave-group kg covers K-half), register-prefetch double staging,
//   144B LDS rows (conflict-free), LDS cross-group reduce + fused epilogue.
// ---------------------------------------------------------------------------
__global__ __launch_bounds__(512) void harsanyi_coop(
    const float* __restrict__ x, const float* __restrict__ vw,
    const float* __restrict__ fcw, unsigned short* __restrict__ xb,
    unsigned short* __restrict__ ltb, unsigned short* __restrict__ wb,
    unsigned short* __restrict__ mb, float* __restrict__ out) {
  const int t = threadIdx.x;
  const int bid = blockIdx.x;

  // ---- Phase A: prep (each element converted exactly once) ----
  {
    // weights: O*I = 1M elems; 256 blocks * 512 threads * 8 = 1M. 
    size_t idx = ((size_t)bid * 512 + t) * 8;
    float4 v0 = *reinterpret_cast<const float4*>(vw + idx);
    float4 v1 = *reinterpret_cast<const float4*>(vw + idx + 4);
    float4 f0 = *reinterpret_cast<const float4*>(fcw + idx);
    float4 f1 = *reinterpret_cast<const float4*>(fcw + idx + 4);
    float va[8] = {v0.x, v0.y, v0.z, v0.w, v1.x, v1.y, v1.z, v1.w};
    float fa[8] = {f0.x, f0.y, f0.z, f0.w, f1.x, f1.y, f1.z, f1.w};
    short8 wv, mv;
#pragma unroll
    for (int j = 0; j < 8; ++j) {
      bool m = va[j] > 0.0f;
      wv[j] = m ? (short)f2bf(fa[j]) : (short)0;
      mv[j] = (short)(m ? 0x3F80 : 0x0000);  // bf16 1.0 / 0.0
    }
    *reinterpret_cast<short8*>(wb + idx) = wv;
    *reinterpret_cast<short8*>(mb + idx) = mv;
  }
  if (t < 128) {
    // x: B*I = 256K elems; 256 blocks * 128 threads * 8 = 256K. 
    size_t idx = ((size_t)bid * 128 + t) * 8;
    float4 x0 = *reinterpret_cast<const float4*>(x + idx);
    float4 x1 = *reinterpret_cast<const float4*>(x + idx + 4);
    float xa[8] = {x0.x, x0.y, x0.z, x0.w, x1.x, x1.y, x1.z, x1.w};
    short8 xv, lv;
#pragma unroll
    for (int j = 0; j < 8; ++j) {
      xv[j] = (short)f2bf(xa[j]);
      lv[j] = (short)f2bf(fast_lt(xa[j]));
    }
    *reinterpret_cast<short8*>(xb + idx) = xv;
    *reinterpret_cast<short8*>(ltb + idx) = lv;
  }

  cooperative_groups::this_grid().sync();

  // ---- Phase B: round-4 GEMM body ----
  const int on0 = (bid & 31) * 32;   // 32 n-blocks
  const int bm0 = (bid >> 5) * 32;   // 8 m-blocks

  __shared__ short As[2][32][72];
  __shared__ short Ls[2][32][72];
  __shared__ short Ws[2][32][72];
  __shared__ short Ms[2][32][72];

  const int lane = t & 63;
  const int wid = t >> 6;            // 0..7
  const int kg = wid >> 2;           // K-group (0: k<512, 1: k>=512)
  const int wm = (wid >> 1) & 1, wn = wid & 1;
  const int lr = lane & 15;
  const int lk = (lane >> 4) * 8;

  const int tl = t & 255;            // thread index within group
  const int srow = tl >> 3;          // staging row 0..31
  const int scol = (tl & 7) * 8;     // staging col (elems)

  const size_t aoff = (size_t)(bm0 + srow) * I_ + kg * 512 + scol;
  const size_t boff = (size_t)(on0 + srow) * I_ + kg * 512 + scol;

  // prefetch tile 0 of this group's K-half
  short8 rx = *reinterpret_cast<const short8*>(xb + aoff);
  short8 rl = *reinterpret_cast<const short8*>(ltb + aoff);
  short8 rw = *reinterpret_cast<const short8*>(wb + boff);
  short8 rm = *reinterpret_cast<const short8*>(mb + boff);

  f32x4 accd = {0.f, 0.f, 0.f, 0.f};
  f32x4 accs = {0.f, 0.f, 0.f, 0.f};

  for (int kt = 0; kt < 512; kt += 64) {
    __syncthreads();  // previous iter's LDS reads done before overwrite
    *reinterpret_cast<short8*>(&As[kg][srow][scol]) = rx;
    *reinterpret_cast<short8*>(&Ls[kg][srow][scol]) = rl;
    *reinterpret_cast<short8*>(&Ws[kg][srow][scol]) = rw;
    *reinterpret_cast<short8*>(&Ms[kg][srow][scol]) = rm;
    if (kt + 64 < 512) {  // issue next-tile loads; latency hides under MFMA
      rx = *reinterpret_cast<const short8*>(xb + aoff + kt + 64);
      rl = *reinterpret_cast<const short8*>(ltb + aoff + kt + 64);
      rw = *reinterpret_cast<const short8*>(wb + boff + kt + 64);
      rm = *reinterpret_cast<const short8*>(mb + boff + kt + 64);
    }
    __syncthreads();
#pragma unroll
    for (int ks = 0; ks < 2; ++ks) {
      const int kb = ks * 32 + lk;
      short8 af = *reinterpret_cast<const short8*>(&As[kg][wm * 16 + lr][kb]);
      short8 lf = *reinterpret_cast<const short8*>(&Ls[kg][wm * 16 + lr][kb]);
      short8 wf = *reinterpret_cast<const short8*>(&Ws[kg][wn * 16 + lr][kb]);
      short8 mf = *reinterpret_cast<const short8*>(&Ms[kg][wn * 16 + lr][kb]);
      accd = __builtin_amdgcn_mfma_f32_16x16x32_bf16(af, wf, accd, 0, 0, 0);
      accs = __builtin_amdgcn_mfma_f32_16x16x32_bf16(lf, mf, accs, 0, 0, 0);
    }
  }

  // Cross-group reduce (group 1 -> LDS, group 0 adds) + fused epilogue.
  __syncthreads();
  float* red = reinterpret_cast<float*>(&As[0][0][0]);  // 8KB needed
  const int ridx = ((wid & 3) * 64 + lane) * 8;
  if (kg == 1) {
#pragma unroll
    for (int r = 0; r < 4; ++r) {
      red[ridx + r] = accd[r];
      red[ridx + 4 + r] = accs[r];
    }
  }
  __syncthreads();
  if (kg == 0) {
    // C/D layout: col = lane&15, row = (lane>>4)*4 + reg   [m89-verified]
    const int orow = bm0 + wm * 16 + (lane >> 4) * 4;
    const int ocol = on0 + wn * 16 + lr;
#pragma unroll
    for (int r = 0; r < 4; ++r) {
      float dsum = accd[r] + red[ridx + r];
      float ssum = accs[r] + red[ridx + 4 + r];
      float d = __expf(ssum);
      float y = fmaxf(dsum * d, 0.0f);
      size_t off = (size_t)(orow + r) * O_ + ocol;
      out[off] = y;
      out[(size_t)B_ * O_ + off] = d;
    }
  }
}

// ---------------------------------------------------------------------------
// fp32 fallback (workspace too small): inline log-tanh, fused epilogue
// ---------------------------------------------------------------------------
__global__ __launch_bounds__(256) void dual_gemm_f32(
    const float* __restrict__ x, const float* __restrict__ vw,
    const float* __restrict__ fcw, float* __restrict__ out) {
  const int on0 = blockIdx.x * 64;
  const int bm0 = blockIdx.y * 64;
  __shared__ float xs[32][68];
  __shared__ float ls[32][68];
  __shared__ float wsm[32][68];
  __shared__ float msh[32][68];
  const int t = threadIdx.x;
  const int tx = t & 15, ty = t >> 4;
  const int m0 = ty * 4, n0 = tx * 4;
  float accd[4][4] = {{0.f}};
  float accs[4][4] = {{0.f}};
  for (int kt = 0; kt < I_; kt += 32) {
#pragma unroll
    for (int j = 0; j < 8; ++j) {
      int f = j * 256 + t;
      int m = f >> 5;
      int kk = f & 31;
      int gk = kt + kk;
      float xv = x[(size_t)(bm0 + m) * I_ + gk];
      xs[kk][m] = xv;
      ls[kk][m] = fast_lt(xv);
      float vv = vw[(size_t)(on0 + m) * I_ + gk];
      float fv = fcw[(size_t)(on0 + m) * I_ + gk];
      float mk = vv > 0.0f ? 1.0f : 0.0f;
      wsm[kk][m] = fv * mk;
      msh[kk][m] = mk;
    }
    __syncthreads();
#pragma unroll
    for (int kk = 0; kk < 32; ++kk) {
      float4 xv = *reinterpret_cast<const float4*>(&xs[kk][m0]);
      float4 lv = *reinterpret_cast<const float4*>(&ls[kk][m0]);
      float4 wv = *reinterpret_cast<const float4*>(&wsm[kk][n0]);
      float4 mv = *reinterpret_cast<const float4*>(&msh[kk][n0]);
      float xa[4] = {xv.x, xv.y, xv.z, xv.w};
      float la[4] = {lv.x, lv.y, lv.z, lv.w};
      float wa[4] = {wv.x, wv.y, wv.z, wv.w};
      float ma[4] = {mv.x, mv.y, mv.z, mv.w};
#pragma unroll
      for (int i = 0; i < 4; ++i)
#pragma unroll
        for (int jj = 0; jj < 4; ++jj) {
          accd[i][jj] = fmaf(xa[i], wa[jj], accd[i][jj]);
          accs[i][jj] = fmaf(la[i], ma[jj], accs[i][jj]);
        }
    }
    __syncthreads();
  }
#pragma unroll
  for (int i = 0; i < 4; ++i) {
    int row = bm0 + m0 + i;
#pragma unroll
    for (int jj = 0; jj < 4; ++jj) {
      float delta = __expf(accs[i][jj]);
      out[(size_t)row * O_ + on0 + n0 + jj] = fmaxf(accd[i][jj] * delta, 0.0f);
      out[(size_t)B_ * O_ + (size_t)row * O_ + on0 + n0 + jj] = delta;
    }
  }
}

extern "C" void kernel_launch(void* const* d_in, const int* in_sizes, int n_in,
                              void* d_out, int out_size, void* d_ws,
                              size_t ws_size, hipStream_t stream) {
  const float* x = (const float*)d_in[0];
  const float* vw = (const float*)d_in[1];
  const float* fcw = (const float*)d_in[2];
  float* out = (float*)d_out;

  const size_t xbB = (size_t)B_ * I_ * 2;  // 512 KB
  const size_t wbB = (size_t)O_ * I_ * 2;  // 2 MB
  const size_t bfB = 2 * xbB + 2 * wbB;    // 5 MB total

  unsigned short* xb = (unsigned short*)d_ws;
  unsigned short* ltb = (unsigned short*)((char*)d_ws + xbB);
  unsigned short* wb = (unsigned short*)((char*)d_ws + 2 * xbB);
  unsigned short* mb = (unsigned short*)((char*)d_ws + 2 * xbB + wbB);

  if (ws_size >= bfB) {
    void* args[] = {(void*)&x, (void*)&vw, (void*)&fcw, (void*)&xb,
                    (void*)&ltb, (void*)&wb, (void*)&mb, (void*)&out};
    hipLaunchCooperativeKernel((const void*)harsanyi_coop, dim3(256), dim3(512),
                               args, 0, stream);
  } else {
    dual_gemm_f32<<<dim3(O_ / 64, B_ / 64, 1), 256, 0, stream>>>(x, vw, fcw, out);
  }
}

// Round 9
// 19.979 us; speedup vs baseline: 2.5589x; 2.5589x over previous
//
#include <hip/hip_runtime.h>
#include <cmath>

// Problem constants (fixed by the reference)
#define B_ 256
#define I_ 1024
#define O_ 1024

typedef __attribute__((ext_vector_type(8))) short short8;   // 8 bf16 = 4 VGPRs
typedef __attribute__((ext_vector_type(4))) float f32x4;

// float -> bf16 bits, round-to-nearest-even (inputs finite after clamp)
__device__ inline unsigned f2bf(float f) {
  union { float f; unsigned u; } c;
  c.f = f;
  unsigned u = c.u;
  return (u + 0x7FFFu + ((u >> 16) & 1u)) >> 16;
}

// fast log(tanh(100|x|)) = log((1-t)/(1+t)), t = e^{-200|x|}  (HW exp/log)
// x==0: log(0) = -inf -> clamped to -1e30; exp(sum)=0 downstream (delta=0). ✓
__device__ inline float fast_lt(float xv) {
  float z = 100.0f * fabsf(xv);
  float t = __expf(-2.0f * z);
  float lt = __logf((1.0f - t) / (1.0f + t));
  return fmaxf(lt, -1e30f);
}

// ---------------------------------------------------------------------------
// Prep (x only): xb = bf16(x), ltb = bf16(log(tanh(100|x|))). 128 blocks.
// Weights are converted inline in the GEMM (cheap VALU, no transcendentals).
// ---------------------------------------------------------------------------
__global__ __launch_bounds__(256) void prep_x(const float* __restrict__ x,
                                              unsigned short* __restrict__ xb,
                                              unsigned short* __restrict__ ltb) {
  int idx = (blockIdx.x * 256 + threadIdx.x) * 8;
  float4 x0 = *reinterpret_cast<const float4*>(x + idx);
  float4 x1 = *reinterpret_cast<const float4*>(x + idx + 4);
  float xa[8] = {x0.x, x0.y, x0.z, x0.w, x1.x, x1.y, x1.z, x1.w};
  short8 xv, lv;
#pragma unroll
  for (int j = 0; j < 8; ++j) {
    xv[j] = (short)f2bf(xa[j]);
    lv[j] = (short)f2bf(fast_lt(xa[j]));
  }
  *reinterpret_cast<short8*>(xb + idx) = xv;
  *reinterpret_cast<short8*>(ltb + idx) = lv;
}

// ---------------------------------------------------------------------------
// Fused dual MFMA GEMM (round-4 skeleton + XCD remap + inline weight convert).
// Tile 32(M) x 32(N); 512 threads = 8 waves; intra-block split-K: wave-group
// kg = wid>>2 covers K-half [kg*512,+512) in 8 iters of BK=64.
// XCD-chunked remap: xcd = bid&7 owns a 4N x 8M rectangle of tiles ->
// per-XCD working set ~2MB (x/lt 1MB + its 128-row vw/fcw slice 1MB),
// L2-resident -> tile re-reads hit L2 instead of L3.
// Weights staged from fp32 and converted in-register while staging (mask =
// vw>0, w = bf16(fc)*mask, m = bf16 1.0/0.0) - exactly-once x conversion
// stays in prep; 8x-redundant weight convert is cheap VALU.
// Cross-group combine: 8KB LDS reduce + fused exp/relu epilogue.
// ---------------------------------------------------------------------------
__global__ __launch_bounds__(512) void mfma_fused4(
    const unsigned short* __restrict__ xb, const unsigned short* __restrict__ ltb,
    const float* __restrict__ vw, const float* __restrict__ fcw,
    float* __restrict__ out) {
  const int bid = blockIdx.x;
  const int cx = bid & 7;            // XCD (round-robin dispatch)
  const int wi = bid >> 3;           // 0..31 within XCD
  const int nblk = cx * 4 + (wi >> 3);  // 0..31
  const int mblk = wi & 7;              // 0..7
  const int on0 = nblk * 32;
  const int bm0 = mblk * 32;

  // 72-short rows = 144B = 9*16B: staging stores and fragment reads spread
  // across all 8 LDS bank-groups (conflict-free for b128 ops).
  __shared__ short As[2][32][72];
  __shared__ short Ls[2][32][72];
  __shared__ short Ws[2][32][72];
  __shared__ short Ms[2][32][72];

  const int t = threadIdx.x;
  const int lane = t & 63;
  const int wid = t >> 6;            // 0..7
  const int kg = wid >> 2;           // K-group (0: k<512, 1: k>=512)
  const int wm = (wid >> 1) & 1, wn = wid & 1;
  const int lr = lane & 15;
  const int lk = (lane >> 4) * 8;

  const int tl = t & 255;            // thread index within group
  const int srow = tl >> 3;          // staging row 0..31
  const int scol = (tl & 7) * 8;     // staging col (elems)

  const size_t aoff = (size_t)(bm0 + srow) * I_ + kg * 512 + scol;
  const size_t boff = (size_t)(on0 + srow) * I_ + kg * 512 + scol;

  // prefetch tile 0 of this group's K-half
  short8 rx = *reinterpret_cast<const short8*>(xb + aoff);
  short8 rl = *reinterpret_cast<const short8*>(ltb + aoff);
  float4 rv0 = *reinterpret_cast<const float4*>(vw + boff);
  float4 rv1 = *reinterpret_cast<const float4*>(vw + boff + 4);
  float4 rf0 = *reinterpret_cast<const float4*>(fcw + boff);
  float4 rf1 = *reinterpret_cast<const float4*>(fcw + boff + 4);

  f32x4 accd = {0.f, 0.f, 0.f, 0.f};
  f32x4 accs = {0.f, 0.f, 0.f, 0.f};

  for (int kt = 0; kt < 512; kt += 64) {
    // convert weight tile in-register (loads had the prev MFMA phase to land)
    float va[8] = {rv0.x, rv0.y, rv0.z, rv0.w, rv1.x, rv1.y, rv1.z, rv1.w};
    float fa[8] = {rf0.x, rf0.y, rf0.z, rf0.w, rf1.x, rf1.y, rf1.z, rf1.w};
    short8 ws_, ms_;
#pragma unroll
    for (int j = 0; j < 8; ++j) {
      bool m = va[j] > 0.0f;
      ws_[j] = m ? (short)f2bf(fa[j]) : (short)0;
      ms_[j] = (short)(m ? 0x3F80 : 0x0000);  // bf16 1.0 / 0.0
    }
    __syncthreads();  // previous iter's LDS reads done before overwrite
    *reinterpret_cast<short8*>(&As[kg][srow][scol]) = rx;
    *reinterpret_cast<short8*>(&Ls[kg][srow][scol]) = rl;
    *reinterpret_cast<short8*>(&Ws[kg][srow][scol]) = ws_;
    *reinterpret_cast<short8*>(&Ms[kg][srow][scol]) = ms_;
    if (kt + 64 < 512) {  // issue next-tile loads; latency hides under MFMA
      rx = *reinterpret_cast<const short8*>(xb + aoff + kt + 64);
      rl = *reinterpret_cast<const short8*>(ltb + aoff + kt + 64);
      rv0 = *reinterpret_cast<const float4*>(vw + boff + kt + 64);
      rv1 = *reinterpret_cast<const float4*>(vw + boff + kt + 68);
      rf0 = *reinterpret_cast<const float4*>(fcw + boff + kt + 64);
      rf1 = *reinterpret_cast<const float4*>(fcw + boff + kt + 68);
    }
    __syncthreads();
#pragma unroll
    for (int ks = 0; ks < 2; ++ks) {
      const int kb = ks * 32 + lk;
      short8 af = *reinterpret_cast<const short8*>(&As[kg][wm * 16 + lr][kb]);
      short8 lf = *reinterpret_cast<const short8*>(&Ls[kg][wm * 16 + lr][kb]);
      short8 wf = *reinterpret_cast<const short8*>(&Ws[kg][wn * 16 + lr][kb]);
      short8 mf = *reinterpret_cast<const short8*>(&Ms[kg][wn * 16 + lr][kb]);
      accd = __builtin_amdgcn_mfma_f32_16x16x32_bf16(af, wf, accd, 0, 0, 0);
      accs = __builtin_amdgcn_mfma_f32_16x16x32_bf16(lf, mf, accs, 0, 0, 0);
    }
  }

  // Cross-group reduce (group 1 -> LDS, group 0 adds) + fused epilogue.
  __syncthreads();
  float* red = reinterpret_cast<float*>(&As[0][0][0]);  // 8KB needed
  const int ridx = ((wid & 3) * 64 + lane) * 8;
  if (kg == 1) {
#pragma unroll
    for (int r = 0; r < 4; ++r) {
      red[ridx + r] = accd[r];
      red[ridx + 4 + r] = accs[r];
    }
  }
  __syncthreads();
  if (kg == 0) {
    // C/D layout: col = lane&15, row = (lane>>4)*4 + reg   [m89-verified]
    const int orow = bm0 + wm * 16 + (lane >> 4) * 4;
    const int ocol = on0 + wn * 16 + lr;
#pragma unroll
    for (int r = 0; r < 4; ++r) {
      float dsum = accd[r] + red[ridx + r];
      float ssum = accs[r] + red[ridx + 4 + r];
      float d = __expf(ssum);
      float y = fmaxf(dsum * d, 0.0f);
      size_t off = (size_t)(orow + r) * O_ + ocol;
      out[off] = y;
      out[(size_t)B_ * O_ + off] = d;
    }
  }
}

// ---------------------------------------------------------------------------
// fp32 fallback (workspace too small): inline log-tanh, fused epilogue
// ---------------------------------------------------------------------------
__global__ __launch_bounds__(256) void dual_gemm_f32(
    const float* __restrict__ x, const float* __restrict__ vw,
    const float* __restrict__ fcw, float* __restrict__ out) {
  const int on0 = blockIdx.x * 64;
  const int bm0 = blockIdx.y * 64;
  __shared__ float xs[32][68];
  __shared__ float ls[32][68];
  __shared__ float wsm[32][68];
  __shared__ float msh[32][68];
  const int t = threadIdx.x;
  const int tx = t & 15, ty = t >> 4;
  const int m0 = ty * 4, n0 = tx * 4;
  float accd[4][4] = {{0.f}};
  float accs[4][4] = {{0.f}};
  for (int kt = 0; kt < I_; kt += 32) {
#pragma unroll
    for (int j = 0; j < 8; ++j) {
      int f = j * 256 + t;
      int m = f >> 5;
      int kk = f & 31;
      int gk = kt + kk;
      float xv = x[(size_t)(bm0 + m) * I_ + gk];
      xs[kk][m] = xv;
      ls[kk][m] = fast_lt(xv);
      float vv = vw[(size_t)(on0 + m) * I_ + gk];
      float fv = fcw[(size_t)(on0 + m) * I_ + gk];
      float mk = vv > 0.0f ? 1.0f : 0.0f;
      wsm[kk][m] = fv * mk;
      msh[kk][m] = mk;
    }
    __syncthreads();
#pragma unroll
    for (int kk = 0; kk < 32; ++kk) {
      float4 xv = *reinterpret_cast<const float4*>(&xs[kk][m0]);
      float4 lv = *reinterpret_cast<const float4*>(&ls[kk][m0]);
      float4 wv = *reinterpret_cast<const float4*>(&wsm[kk][n0]);
      float4 mv = *reinterpret_cast<const float4*>(&msh[kk][n0]);
      float xa[4] = {xv.x, xv.y, xv.z, xv.w};
      float la[4] = {lv.x, lv.y, lv.z, lv.w};
      float wa[4] = {wv.x, wv.y, wv.z, wv.w};
      float ma[4] = {mv.x, mv.y, mv.z, mv.w};
#pragma unroll
      for (int i = 0; i < 4; ++i)
#pragma unroll
        for (int jj = 0; jj < 4; ++jj) {
          accd[i][jj] = fmaf(xa[i], wa[jj], accd[i][jj]);
          accs[i][jj] = fmaf(la[i], ma[jj], accs[i][jj]);
        }
    }
    __syncthreads();
  }
#pragma unroll
  for (int i = 0; i < 4; ++i) {
    int row = bm0 + m0 + i;
#pragma unroll
    for (int jj = 0; jj < 4; ++jj) {
      float delta = __expf(accs[i][jj]);
      out[(size_t)row * O_ + on0 + n0 + jj] = fmaxf(accd[i][jj] * delta, 0.0f);
      out[(size_t)B_ * O_ + (size_t)row * O_ + on0 + n0 + jj] = delta;
    }
  }
}

extern "C" void kernel_launch(void* const* d_in, const int* in_sizes, int n_in,
                              void* d_out, int out_size, void* d_ws,
                              size_t ws_size, hipStream_t stream) {
  const float* x = (const float*)d_in[0];
  const float* vw = (const float*)d_in[1];
  const float* fcw = (const float*)d_in[2];
  float* out = (float*)d_out;

  const size_t xbB = (size_t)B_ * I_ * 2;  // 512 KB
  const size_t needB = 2 * xbB;            // 1 MB total

  unsigned short* xb = (unsigned short*)d_ws;
  unsigned short* ltb = (unsigned short*)((char*)d_ws + xbB);

  if (ws_size >= needB) {
    prep_x<<<(B_ * I_) / 2048, 256, 0, stream>>>(x, xb, ltb);
    mfma_fused4<<<256, 512, 0, stream>>>(xb, ltb, vw, fcw, out);
  } else {
    dual_gemm_f32<<<dim3(O_ / 64, B_ / 64, 1), 256, 0, stream>>>(x, vw, fcw, out);
  }
}

// Round 10
// 17.143 us; speedup vs baseline: 2.9822x; 1.1654x over previous
//
#include <hip/hip_runtime.h>
#include <cmath>

// Problem constants (fixed by the reference)
#define B_ 256
#define I_ 1024
#define O_ 1024

typedef __attribute__((ext_vector_type(8))) short short8;   // 8 bf16 = 4 VGPRs
typedef __attribute__((ext_vector_type(4))) float f32x4;

// float -> bf16 bits, round-to-nearest-even (inputs finite after clamp)
__device__ inline unsigned f2bf(float f) {
  union { float f; unsigned u; } c;
  c.f = f;
  unsigned u = c.u;
  return (u + 0x7FFFu + ((u >> 16) & 1u)) >> 16;
}

// fast log(tanh(100|x|)) = log((1-t)/(1+t)), t = e^{-200|x|}  (HW exp/log)
// x==0: log(0) = -inf -> clamped to -1e30; exp(sum)=0 downstream (delta=0). ✓
__device__ inline float fast_lt(float xv) {
  float z = 100.0f * fabsf(xv);
  float t = __expf(-2.0f * z);
  float lt = __logf((1.0f - t) / (1.0f + t));
  return fmaxf(lt, -1e30f);
}

// ---------------------------------------------------------------------------
// Prep: 256 blocks x 512 threads (one pass over all CUs).
//   all threads: wb = bf16(fc * (vw>0)), 8 elems each  (mask NOT stored --
//                derived in the GEMM from wb != 0; fc never rounds to bf16 0
//                for this distribution except exact 0, measure-zero)
//   threads 0..127: xb = bf16(x), ltb = bf16(log(tanh(100|x|))), 8 elems each
// ---------------------------------------------------------------------------
__global__ __launch_bounds__(512) void prep2(
    const float* __restrict__ x, const float* __restrict__ vw,
    const float* __restrict__ fcw, unsigned short* __restrict__ xb,
    unsigned short* __restrict__ ltb, unsigned short* __restrict__ wb) {
  const int t = threadIdx.x;
  const int bid = blockIdx.x;
  {
    size_t idx = ((size_t)bid * 512 + t) * 8;
    float4 v0 = *reinterpret_cast<const float4*>(vw + idx);
    float4 v1 = *reinterpret_cast<const float4*>(vw + idx + 4);
    float4 f0 = *reinterpret_cast<const float4*>(fcw + idx);
    float4 f1 = *reinterpret_cast<const float4*>(fcw + idx + 4);
    float va[8] = {v0.x, v0.y, v0.z, v0.w, v1.x, v1.y, v1.z, v1.w};
    float fa[8] = {f0.x, f0.y, f0.z, f0.w, f1.x, f1.y, f1.z, f1.w};
    short8 wv;
#pragma unroll
    for (int j = 0; j < 8; ++j)
      wv[j] = (va[j] > 0.0f) ? (short)f2bf(fa[j]) : (short)0;
    *reinterpret_cast<short8*>(wb + idx) = wv;
  }
  if (t < 128) {
    size_t idx = ((size_t)bid * 128 + t) * 8;
    float4 x0 = *reinterpret_cast<const float4*>(x + idx);
    float4 x1 = *reinterpret_cast<const float4*>(x + idx + 4);
    float xa[8] = {x0.x, x0.y, x0.z, x0.w, x1.x, x1.y, x1.z, x1.w};
    short8 xv, lv;
#pragma unroll
    for (int j = 0; j < 8; ++j) {
      xv[j] = (short)f2bf(xa[j]);
      lv[j] = (short)f2bf(fast_lt(xa[j]));
    }
    *reinterpret_cast<short8*>(xb + idx) = xv;
    *reinterpret_cast<short8*>(ltb + idx) = lv;
  }
}

// ---------------------------------------------------------------------------
// Fused dual MFMA GEMM (R4 skeleton + XCD remap + mask derived from wb).
// Tile 32(M) x 32(N); 512 threads = 8 waves; intra-block split-K: wave-group
// kg = wid>>2 covers K-half [kg*512,+512) in 8 iters of BK=64.
// 3 global streams (xb, ltb, wb); mask tile derived in-register at stage
// time (wb != 0 -> bf16 1.0). 72-short LDS rows (144B = 9*16B, conflict-free
// for both b128 stores and fragment reads).
// XCD remap: xcd = bid&7 owns n-blocks [4*xcd, +4) x all m -> ~1.3MB/XCD,
// L2-resident re-reads.
// Cross-group combine: 8KB LDS reduce + fused exp/relu epilogue.
// ---------------------------------------------------------------------------
__global__ __launch_bounds__(512) void mfma_fused5(
    const unsigned short* __restrict__ xb, const unsigned short* __restrict__ ltb,
    const unsigned short* __restrict__ wb, float* __restrict__ out) {
  const int bid = blockIdx.x;
  const int cx = bid & 7;               // XCD (round-robin dispatch)
  const int wi = bid >> 3;              // 0..31 within XCD
  const int nblk = cx * 4 + (wi >> 3);  // 0..31
  const int mblk = wi & 7;              // 0..7
  const int on0 = nblk * 32;
  const int bm0 = mblk * 32;

  __shared__ short As[2][32][72];
  __shared__ short Ls[2][32][72];
  __shared__ short Ws[2][32][72];
  __shared__ short Ms[2][32][72];

  const int t = threadIdx.x;
  const int lane = t & 63;
  const int wid = t >> 6;            // 0..7
  const int kg = wid >> 2;           // K-group (0: k<512, 1: k>=512)
  const int wm = (wid >> 1) & 1, wn = wid & 1;
  const int lr = lane & 15;
  const int lk = (lane >> 4) * 8;

  const int tl = t & 255;            // thread index within group
  const int srow = tl >> 3;          // staging row 0..31
  const int scol = (tl & 7) * 8;     // staging col (elems)

  const size_t aoff = (size_t)(bm0 + srow) * I_ + kg * 512 + scol;
  const size_t boff = (size_t)(on0 + srow) * I_ + kg * 512 + scol;

  // prefetch tile 0 of this group's K-half
  short8 rx = *reinterpret_cast<const short8*>(xb + aoff);
  short8 rl = *reinterpret_cast<const short8*>(ltb + aoff);
  short8 rw = *reinterpret_cast<const short8*>(wb + boff);

  f32x4 accd = {0.f, 0.f, 0.f, 0.f};
  f32x4 accs = {0.f, 0.f, 0.f, 0.f};

  for (int kt = 0; kt < 512; kt += 64) {
    // derive mask tile in-register: m = (wb != 0) ? bf16 1.0 : 0
    short8 rm;
#pragma unroll
    for (int j = 0; j < 8; ++j)
      rm[j] = rw[j] ? (short)0x3F80 : (short)0;
    __syncthreads();  // previous iter's LDS reads done before overwrite
    *reinterpret_cast<short8*>(&As[kg][srow][scol]) = rx;
    *reinterpret_cast<short8*>(&Ls[kg][srow][scol]) = rl;
    *reinterpret_cast<short8*>(&Ws[kg][srow][scol]) = rw;
    *reinterpret_cast<short8*>(&Ms[kg][srow][scol]) = rm;
    if (kt + 64 < 512) {  // issue next-tile loads; latency hides under MFMA
      rx = *reinterpret_cast<const short8*>(xb + aoff + kt + 64);
      rl = *reinterpret_cast<const short8*>(ltb + aoff + kt + 64);
      rw = *reinterpret_cast<const short8*>(wb + boff + kt + 64);
    }
    __syncthreads();
#pragma unroll
    for (int ks = 0; ks < 2; ++ks) {
      const int kb = ks * 32 + lk;
      short8 af = *reinterpret_cast<const short8*>(&As[kg][wm * 16 + lr][kb]);
      short8 lf = *reinterpret_cast<const short8*>(&Ls[kg][wm * 16 + lr][kb]);
      short8 wf = *reinterpret_cast<const short8*>(&Ws[kg][wn * 16 + lr][kb]);
      short8 mf = *reinterpret_cast<const short8*>(&Ms[kg][wn * 16 + lr][kb]);
      accd = __builtin_amdgcn_mfma_f32_16x16x32_bf16(af, wf, accd, 0, 0, 0);
      accs = __builtin_amdgcn_mfma_f32_16x16x32_bf16(lf, mf, accs, 0, 0, 0);
    }
  }

  // Cross-group reduce (group 1 -> LDS, group 0 adds) + fused epilogue.
  __syncthreads();
  float* red = reinterpret_cast<float*>(&As[0][0][0]);  // 8KB needed
  const int ridx = ((wid & 3) * 64 + lane) * 8;
  if (kg == 1) {
#pragma unroll
    for (int r = 0; r < 4; ++r) {
      red[ridx + r] = accd[r];
      red[ridx + 4 + r] = accs[r];
    }
  }
  __syncthreads();
  if (kg == 0) {
    // C/D layout: col = lane&15, row = (lane>>4)*4 + reg   [m89-verified]
    const int orow = bm0 + wm * 16 + (lane >> 4) * 4;
    const int ocol = on0 + wn * 16 + lr;
#pragma unroll
    for (int r = 0; r < 4; ++r) {
      float dsum = accd[r] + red[ridx + r];
      float ssum = accs[r] + red[ridx + 4 + r];
      float d = __expf(ssum);
      float y = fmaxf(dsum * d, 0.0f);
      size_t off = (size_t)(orow + r) * O_ + ocol;
      out[off] = y;
      out[(size_t)B_ * O_ + off] = d;
    }
  }
}

// ---------------------------------------------------------------------------
// fp32 fallback (workspace too small): inline log-tanh, fused epilogue
// ---------------------------------------------------------------------------
__global__ __launch_bounds__(256) void dual_gemm_f32(
    const float* __restrict__ x, const float* __restrict__ vw,
    const float* __restrict__ fcw, float* __restrict__ out) {
  const int on0 = blockIdx.x * 64;
  const int bm0 = blockIdx.y * 64;
  __shared__ float xs[32][68];
  __shared__ float ls[32][68];
  __shared__ float wsm[32][68];
  __shared__ float msh[32][68];
  const int t = threadIdx.x;
  const int tx = t & 15, ty = t >> 4;
  const int m0 = ty * 4, n0 = tx * 4;
  float accd[4][4] = {{0.f}};
  float accs[4][4] = {{0.f}};
  for (int kt = 0; kt < I_; kt += 32) {
#pragma unroll
    for (int j = 0; j < 8; ++j) {
      int f = j * 256 + t;
      int m = f >> 5;
      int kk = f & 31;
      int gk = kt + kk;
      float xv = x[(size_t)(bm0 + m) * I_ + gk];
      xs[kk][m] = xv;
      ls[kk][m] = fast_lt(xv);
      float vv = vw[(size_t)(on0 + m) * I_ + gk];
      float fv = fcw[(size_t)(on0 + m) * I_ + gk];
      float mk = vv > 0.0f ? 1.0f : 0.0f;
      wsm[kk][m] = fv * mk;
      msh[kk][m] = mk;
    }
    __syncthreads();
#pragma unroll
    for (int kk = 0; kk < 32; ++kk) {
      float4 xv = *reinterpret_cast<const float4*>(&xs[kk][m0]);
      float4 lv = *reinterpret_cast<const float4*>(&ls[kk][m0]);
      float4 wv = *reinterpret_cast<const float4*>(&wsm[kk][n0]);
      float4 mv = *reinterpret_cast<const float4*>(&msh[kk][n0]);
      float xa[4] = {xv.x, xv.y, xv.z, xv.w};
      float la[4] = {lv.x, lv.y, lv.z, lv.w};
      float wa[4] = {wv.x, wv.y, wv.z, wv.w};
      float ma[4] = {mv.x, mv.y, mv.z, mv.w};
#pragma unroll
      for (int i = 0; i < 4; ++i)
#pragma unroll
        for (int jj = 0; jj < 4; ++jj) {
          accd[i][jj] = fmaf(xa[i], wa[jj], accd[i][jj]);
          accs[i][jj] = fmaf(la[i], ma[jj], accs[i][jj]);
        }
    }
    __syncthreads();
  }
#pragma unroll
  for (int i = 0; i < 4; ++i) {
    int row = bm0 + m0 + i;
#pragma unroll
    for (int jj = 0; jj < 4; ++jj) {
      float delta = __expf(accs[i][jj]);
      out[(size_t)row * O_ + on0 + n0 + jj] = fmaxf(accd[i][jj] * delta, 0.0f);
      out[(size_t)B_ * O_ + (size_t)row * O_ + on0 + n0 + jj] = delta;
    }
  }
}

extern "C" void kernel_launch(void* const* d_in, const int* in_sizes, int n_in,
                              void* d_out, int out_size, void* d_ws,
                              size_t ws_size, hipStream_t stream) {
  const float* x = (const float*)d_in[0];
  const float* vw = (const float*)d_in[1];
  const float* fcw = (const float*)d_in[2];
  float* out = (float*)d_out;

  const size_t xbB = (size_t)B_ * I_ * 2;  // 512 KB
  const size_t wbB = (size_t)O_ * I_ * 2;  // 2 MB
  const size_t needB = 2 * xbB + wbB;      // 3 MB total

  unsigned short* xb = (unsigned short*)d_ws;
  unsigned short* ltb = (unsigned short*)((char*)d_ws + xbB);
  unsigned short* wb = (unsigned short*)((char*)d_ws + 2 * xbB);

  if (ws_size >= needB) {
    prep2<<<256, 512, 0, stream>>>(x, vw, fcw, xb, ltb, wb);
    mfma_fused5<<<256, 512, 0, stream>>>(xb, ltb, wb, out);
  } else {
    dual_gemm_f32<<<dim3(O_ / 64, B_ / 64, 1), 256, 0, stream>>>(x, vw, fcw, out);
  }
}

// Round 11
// 16.298 us; speedup vs baseline: 3.1368x; 1.0519x over previous
//
#include <hip/hip_runtime.h>
#include <cmath>

// Problem constants (fixed by the reference)
#define B_ 256
#define I_ 1024
#define O_ 1024

typedef __attribute__((ext_vector_type(8))) short short8;   // 8 bf16 = 4 VGPRs
typedef __attribute__((ext_vector_type(4))) float f32x4;

// float -> bf16 bits, round-to-nearest-even (inputs finite after clamp)
__device__ inline unsigned f2bf(float f) {
  union { float f; unsigned u; } c;
  c.f = f;
  unsigned u = c.u;
  return (u + 0x7FFFu + ((u >> 16) & 1u)) >> 16;
}

// fast log(tanh(100|x|)) = log((1-t)/(1+t)), t = e^{-200|x|}  (HW exp/log)
// x==0: log(0) = -inf -> clamped to -1e30; exp(sum)=0 downstream (delta=0). ✓
__device__ inline float fast_lt(float xv) {
  float z = 100.0f * fabsf(xv);
  float t = __expf(-2.0f * z);
  float lt = __logf((1.0f - t) / (1.0f + t));
  return fmaxf(lt, -1e30f);
}

// ---------------------------------------------------------------------------
// Prep (unchanged from R10): 256 blocks x 512 threads.
//   all threads: wb = bf16(fc * (vw>0)), 8 elems each (mask derived later
//                from wb != 0; fc never bf16-rounds to 0 for this dist)
//   threads 0..127: xb = bf16(x), ltb = bf16(log(tanh(100|x|)))
// ---------------------------------------------------------------------------
__global__ __launch_bounds__(512) void prep2(
    const float* __restrict__ x, const float* __restrict__ vw,
    const float* __restrict__ fcw, unsigned short* __restrict__ xb,
    unsigned short* __restrict__ ltb, unsigned short* __restrict__ wb) {
  const int t = threadIdx.x;
  const int bid = blockIdx.x;
  {
    size_t idx = ((size_t)bid * 512 + t) * 8;
    float4 v0 = *reinterpret_cast<const float4*>(vw + idx);
    float4 v1 = *reinterpret_cast<const float4*>(vw + idx + 4);
    float4 f0 = *reinterpret_cast<const float4*>(fcw + idx);
    float4 f1 = *reinterpret_cast<const float4*>(fcw + idx + 4);
    float va[8] = {v0.x, v0.y, v0.z, v0.w, v1.x, v1.y, v1.z, v1.w};
    float fa[8] = {f0.x, f0.y, f0.z, f0.w, f1.x, f1.y, f1.z, f1.w};
    short8 wv;
#pragma unroll
    for (int j = 0; j < 8; ++j)
      wv[j] = (va[j] > 0.0f) ? (short)f2bf(fa[j]) : (short)0;
    *reinterpret_cast<short8*>(wb + idx) = wv;
  }
  if (t < 128) {
    size_t idx = ((size_t)bid * 128 + t) * 8;
    float4 x0 = *reinterpret_cast<const float4*>(x + idx);
    float4 x1 = *reinterpret_cast<const float4*>(x + idx + 4);
    float xa[8] = {x0.x, x0.y, x0.z, x0.w, x1.x, x1.y, x1.z, x1.w};
    short8 xv, lv;
#pragma unroll
    for (int j = 0; j < 8; ++j) {
      xv[j] = (short)f2bf(xa[j]);
      lv[j] = (short)f2bf(fast_lt(xa[j]));
    }
    *reinterpret_cast<short8*>(xb + idx) = xv;
    *reinterpret_cast<short8*>(ltb + idx) = lv;
  }
}

// ---------------------------------------------------------------------------
// Dual MFMA GEMM, LDS-traffic-minimized.
// Tile 32(M) x 32(N); 512 threads = 8 waves = 4 K-groups x 2 waves.
// kg = wid>>1 covers K-quarter [kg*256,+256) in 4 iters of BK=64; the 2
// waves in a group split M (w2*16): each wave computes a 16x32 output slab
// of BOTH GEMMs -> per ks reads {af, lf, wf0, wf1} = 4 frags for 4 MFMAs
// (1.0 frag/MFMA; R4 was 2.0). Mask fragment derived in-register from wf
// (wb!=0 -> bf16 1.0) - no Ms array at all.
// LDS: [kg][3][32][72] shorts (54KB); 144B rows = 9x16B granules ->
// conflict-free b128 stores+reads (R4-verified pattern).
// Cross-group: 4-way LDS reduce (24KB, reusing lds) + fused exp/relu epilogue.
// XCD remap: xcd = bid&7 owns 4 consecutive n-blocks x all m.
// ---------------------------------------------------------------------------
__global__ __launch_bounds__(512) void mfma_fused6(
    const unsigned short* __restrict__ xb, const unsigned short* __restrict__ ltb,
    const unsigned short* __restrict__ wb, float* __restrict__ out) {
  const int bid = blockIdx.x;
  const int cx = bid & 7;               // XCD (round-robin dispatch)
  const int wi = bid >> 3;              // 0..31 within XCD
  const int nblk = cx * 4 + (wi >> 3);  // 0..31
  const int mblk = wi & 7;              // 0..7
  const int on0 = nblk * 32;
  const int bm0 = mblk * 32;

  __shared__ short lds[4][3][32][72];   // [kg][A,L,W][row][col]

  const int t = threadIdx.x;
  const int lane = t & 63;
  const int wid = t >> 6;            // 0..7
  const int kg = wid >> 1;           // K-group 0..3: K-quarter [kg*256,+256)
  const int w2 = wid & 1;            // wave within group: m-half
  const int lr = lane & 15;
  const int lk = (lane >> 4) * 8;

  const int tl = t & 127;            // thread index within group
  const int srow = tl >> 2;          // staging row 0..31
  const int scol = (tl & 3) * 16;    // staging col (elems): 0,16,32,48

  const size_t aoff = (size_t)(bm0 + srow) * I_ + kg * 256 + scol;
  const size_t boff = (size_t)(on0 + srow) * I_ + kg * 256 + scol;

  // prefetch tile 0 of this group's K-quarter (3 streams x 2 chunks)
  short8 rx0 = *reinterpret_cast<const short8*>(xb + aoff);
  short8 rx1 = *reinterpret_cast<const short8*>(xb + aoff + 8);
  short8 rl0 = *reinterpret_cast<const short8*>(ltb + aoff);
  short8 rl1 = *reinterpret_cast<const short8*>(ltb + aoff + 8);
  short8 rw0 = *reinterpret_cast<const short8*>(wb + boff);
  short8 rw1 = *reinterpret_cast<const short8*>(wb + boff + 8);

  f32x4 z = {0.f, 0.f, 0.f, 0.f};
  f32x4 accd0 = z, accd1 = z, accs0 = z, accs1 = z;

  for (int kt = 0; kt < 256; kt += 64) {
    __syncthreads();  // previous iter's LDS reads done before overwrite
    *reinterpret_cast<short8*>(&lds[kg][0][srow][scol]) = rx0;
    *reinterpret_cast<short8*>(&lds[kg][0][srow][scol + 8]) = rx1;
    *reinterpret_cast<short8*>(&lds[kg][1][srow][scol]) = rl0;
    *reinterpret_cast<short8*>(&lds[kg][1][srow][scol + 8]) = rl1;
    *reinterpret_cast<short8*>(&lds[kg][2][srow][scol]) = rw0;
    *reinterpret_cast<short8*>(&lds[kg][2][srow][scol + 8]) = rw1;
    if (kt + 64 < 256) {  // issue next-tile loads; latency hides under MFMA
      rx0 = *reinterpret_cast<const short8*>(xb + aoff + kt + 64);
      rx1 = *reinterpret_cast<const short8*>(xb + aoff + kt + 72);
      rl0 = *reinterpret_cast<const short8*>(ltb + aoff + kt + 64);
      rl1 = *reinterpret_cast<const short8*>(ltb + aoff + kt + 72);
      rw0 = *reinterpret_cast<const short8*>(wb + boff + kt + 64);
      rw1 = *reinterpret_cast<const short8*>(wb + boff + kt + 72);
    }
    __syncthreads();
#pragma unroll
    for (int ks = 0; ks < 2; ++ks) {
      const int kb = ks * 32 + lk;
      short8 af = *reinterpret_cast<const short8*>(&lds[kg][0][w2 * 16 + lr][kb]);
      short8 lf = *reinterpret_cast<const short8*>(&lds[kg][1][w2 * 16 + lr][kb]);
      short8 wf0 = *reinterpret_cast<const short8*>(&lds[kg][2][lr][kb]);
      short8 wf1 = *reinterpret_cast<const short8*>(&lds[kg][2][16 + lr][kb]);
      short8 mf0, mf1;
#pragma unroll
      for (int j = 0; j < 8; ++j) {
        mf0[j] = wf0[j] ? (short)0x3F80 : (short)0;
        mf1[j] = wf1[j] ? (short)0x3F80 : (short)0;
      }
      accd0 = __builtin_amdgcn_mfma_f32_16x16x32_bf16(af, wf0, accd0, 0, 0, 0);
      accd1 = __builtin_amdgcn_mfma_f32_16x16x32_bf16(af, wf1, accd1, 0, 0, 0);
      accs0 = __builtin_amdgcn_mfma_f32_16x16x32_bf16(lf, mf0, accs0, 0, 0, 0);
      accs1 = __builtin_amdgcn_mfma_f32_16x16x32_bf16(lf, mf1, accs1, 0, 0, 0);
    }
  }

  // Cross-group reduce: kg 1..3 write 16 floats/lane, kg 0 accumulates.
  __syncthreads();
  float* red = reinterpret_cast<float*>(&lds[0][0][0][0]);  // 24KB < 54KB
  if (kg > 0) {
    float* p = red + (((kg - 1) * 128 + w2 * 64 + lane) << 4);
#pragma unroll
    for (int r = 0; r < 4; ++r) {
      p[r] = accd0[r];
      p[4 + r] = accd1[r];
      p[8 + r] = accs0[r];
      p[12 + r] = accs1[r];
    }
  }
  __syncthreads();
  if (kg == 0) {
#pragma unroll
    for (int g = 0; g < 3; ++g) {
      const float* p = red + ((g * 128 + w2 * 64 + lane) << 4);
#pragma unroll
      for (int r = 0; r < 4; ++r) {
        accd0[r] += p[r];
        accd1[r] += p[4 + r];
        accs0[r] += p[8 + r];
        accs1[r] += p[12 + r];
      }
    }
    // C/D layout: col = lane&15, row = (lane>>4)*4 + reg   [m89-verified]
    const int orow = bm0 + w2 * 16 + (lane >> 4) * 4;
    const int ocol = on0 + lr;
#pragma unroll
    for (int r = 0; r < 4; ++r) {
      float d0 = __expf(accs0[r]);
      float d1 = __expf(accs1[r]);
      float y0 = fmaxf(accd0[r] * d0, 0.0f);
      float y1 = fmaxf(accd1[r] * d1, 0.0f);
      size_t off0 = (size_t)(orow + r) * O_ + ocol;
      out[off0] = y0;
      out[off0 + 16] = y1;
      out[(size_t)B_ * O_ + off0] = d0;
      out[(size_t)B_ * O_ + off0 + 16] = d1;
    }
  }
}

// ---------------------------------------------------------------------------
// fp32 fallback (workspace too small): inline log-tanh, fused epilogue
// ---------------------------------------------------------------------------
__global__ __launch_bounds__(256) void dual_gemm_f32(
    const float* __restrict__ x, const float* __restrict__ vw,
    const float* __restrict__ fcw, float* __restrict__ out) {
  const int on0 = blockIdx.x * 64;
  const int bm0 = blockIdx.y * 64;
  __shared__ float xs[32][68];
  __shared__ float ls[32][68];
  __shared__ float wsm[32][68];
  __shared__ float msh[32][68];
  const int t = threadIdx.x;
  const int tx = t & 15, ty = t >> 4;
  const int m0 = ty * 4, n0 = tx * 4;
  float accd[4][4] = {{0.f}};
  float accs[4][4] = {{0.f}};
  for (int kt = 0; kt < I_; kt += 32) {
#pragma unroll
    for (int j = 0; j < 8; ++j) {
      int f = j * 256 + t;
      int m = f >> 5;
      int kk = f & 31;
      int gk = kt + kk;
      float xv = x[(size_t)(bm0 + m) * I_ + gk];
      xs[kk][m] = xv;
      ls[kk][m] = fast_lt(xv);
      float vv = vw[(size_t)(on0 + m) * I_ + gk];
      float fv = fcw[(size_t)(on0 + m) * I_ + gk];
      float mk = vv > 0.0f ? 1.0f : 0.0f;
      wsm[kk][m] = fv * mk;
      msh[kk][m] = mk;
    }
    __syncthreads();
#pragma unroll
    for (int kk = 0; kk < 32; ++kk) {
      float4 xv = *reinterpret_cast<const float4*>(&xs[kk][m0]);
      float4 lv = *reinterpret_cast<const float4*>(&ls[kk][m0]);
      float4 wv = *reinterpret_cast<const float4*>(&wsm[kk][n0]);
      float4 mv = *reinterpret_cast<const float4*>(&msh[kk][n0]);
      float xa[4] = {xv.x, xv.y, xv.z, xv.w};
      float la[4] = {lv.x, lv.y, lv.z, lv.w};
      float wa[4] = {wv.x, wv.y, wv.z, wv.w};
      float ma[4] = {mv.x, mv.y, mv.z, mv.w};
#pragma unroll
      for (int i = 0; i < 4; ++i)
#pragma unroll
        for (int jj = 0; jj < 4; ++jj) {
          accd[i][jj] = fmaf(xa[i], wa[jj], accd[i][jj]);
          accs[i][jj] = fmaf(la[i], ma[jj], accs[i][jj]);
        }
    }
    __syncthreads();
  }
#pragma unroll
  for (int i = 0; i < 4; ++i) {
    int row = bm0 + m0 + i;
#pragma unroll
    for (int jj = 0; jj < 4; ++jj) {
      float delta = __expf(accs[i][jj]);
      out[(size_t)row * O_ + on0 + n0 + jj] = fmaxf(accd[i][jj] * delta, 0.0f);
      out[(size_t)B_ * O_ + (size_t)row * O_ + on0 + n0 + jj] = delta;
    }
  }
}

extern "C" void kernel_launch(void* const* d_in, const int* in_sizes, int n_in,
                              void* d_out, int out_size, void* d_ws,
                              size_t ws_size, hipStream_t stream) {
  const float* x = (const float*)d_in[0];
  const float* vw = (const float*)d_in[1];
  const float* fcw = (const float*)d_in[2];
  float* out = (float*)d_out;

  const size_t xbB = (size_t)B_ * I_ * 2;  // 512 KB
  const size_t wbB = (size_t)O_ * I_ * 2;  // 2 MB
  const size_t needB = 2 * xbB + wbB;      // 3 MB total

  unsigned short* xb = (unsigned short*)d_ws;
  unsigned short* ltb = (unsigned short*)((char*)d_ws + xbB);
  unsigned short* wb = (unsigned short*)((char*)d_ws + 2 * xbB);

  if (ws_size >= needB) {
    prep2<<<256, 512, 0, stream>>>(x, vw, fcw, xb, ltb, wb);
    mfma_fused6<<<256, 512, 0, stream>>>(xb, ltb, wb, out);
  } else {
    dual_gemm_f32<<<dim3(O_ / 64, B_ / 64, 1), 256, 0, stream>>>(x, vw, fcw, out);
  }
}